// Round 11
// baseline (142.651 us; speedup 1.0000x reference)
//
#include <hip/hip_runtime.h>
#include <hip/hip_bf16.h>
#include <cmath>
#include <stdint.h>

#define B_ 4
#define M_ 1024
#define N_ 2048
#define D_ 1024
#define H_ 16
#define DH_ 64
#define NT 64      // N tile
#define NTH 16     // tiles per half (N split 2-way inside the block)
#define PITCH 72   // prep LDS pitch (bf16)

typedef __bf16 bf16_t;
typedef __attribute__((ext_vector_type(8))) __bf16 bf16x8;
typedef __attribute__((ext_vector_type(16))) float f32x16;
typedef __attribute__((ext_vector_type(2))) float f32x2;

static __device__ __forceinline__ float silu_f(float x) {
  return x / (1.0f + __expf(-x));
}

// pack two f32 -> two bf16 in one u32 (v_cvt_pk_bf16_f32)
static __device__ __forceinline__ unsigned pk2(float a, float b) {
  union { __bf16 h[2]; unsigned u; } p;
  p.h[0] = (__bf16)a; p.h[1] = (__bf16)b;
  return p.u;
}

// async global->LDS, 16B/lane; LDS dest is wave-uniform base + lane*16
static __device__ __forceinline__ void gload16(const bf16_t* g, bf16_t* l) {
  typedef __attribute__((address_space(1))) const unsigned GU;
  typedef __attribute__((address_space(3))) unsigned LU;
  __builtin_amdgcn_global_load_lds((GU*)(const unsigned*)g, (LU*)(unsigned*)l,
                                   16, 0, 0);
}

// swap bits 2 and 3 of a row index (involution) — K-row permutation so the
// QK^T C-layout registers land directly in PV B-fragment order.
static __device__ __forceinline__ int sw23(int x) {
  return (x & ~12) | ((x & 4) << 1) | ((x & 8) >> 1);
}

// ---- prep ---- (r6 version, verified)
// K' = L2norm(silu(kv heads)), ZEROED for masked n, in MFMA A-FRAGMENT order:
//   kp elem addr = bh*131072 + (tile*8 + nb*4 + kk)*512 + (hi*32+sw23(l31))*8+j
// V^T (raw kv heads), ZEROED for masked n, ALSO in A-fragment order:
//   vt elem addr = bh*131072 + (tile*8 + i*4 + ks)*512 + (hi*32+l31)*8 + j
// Frag-order is ALSO the DMA/LDS-read order: gload16 copies a frag linearly,
// ds_read_b128 at lane*16 is conflict-free. Mask bits packed.
__global__ __launch_bounds__(256) void prep_kernel(
    const float* __restrict__ kv, const int* __restrict__ kv_mask,
    bf16_t* __restrict__ kp, bf16_t* __restrict__ vt,
    unsigned long long* __restrict__ mb) {
  __shared__ __align__(16) bf16_t Lt[NT][PITCH];
  const int bx = blockIdx.x;
  const int hp = bx & 7;
  const int nt = (bx >> 3) & 31;
  const int b  = bx >> 8;
  const int n0 = nt * NT;
  const int tid = threadIdx.x;
  const float keep = kv_mask[b * N_ + n0 + (tid >> 2)] ? 0.f : 1.f;

  #pragma unroll
  for (int hi = 0; hi < 2; ++hi) {
    const int h = hp * 2 + hi;
    const size_t bh = (size_t)(b * H_ + h);
    {
      const int r = tid >> 2, c0 = (tid & 3) * 16;
      const float* src = kv + ((size_t)(b * N_ + n0 + r)) * D_ + h * DH_ + c0;
      union { float f[16]; float4 v4[4]; } raw;
      raw.v4[0] = *(const float4*)(src + 0);
      raw.v4[1] = *(const float4*)(src + 4);
      raw.v4[2] = *(const float4*)(src + 8);
      raw.v4[3] = *(const float4*)(src + 12);
      float sv[16];
      float ss = 0.f;
      #pragma unroll
      for (int i = 0; i < 16; ++i) { sv[i] = silu_f(raw.f[i]); ss += sv[i] * sv[i]; }
      ss += __shfl_xor(ss, 1); ss += __shfl_xor(ss, 2);
      const float inv = keep / fmaxf(sqrtf(ss), 1e-6f);  // 0 for masked rows
      union { bf16_t bs[16]; uint4 u[2]; } pk;
      #pragma unroll
      for (int i = 0; i < 16; ++i) pk.bs[i] = (bf16_t)(sv[i] * inv);
      // fragment-order K' write: kk = tid&3, nb = r>>5, lane-row sw23(r&31)
      const size_t fbase = bh * 131072 +
          (size_t)((nt * 8 + (r >> 5) * 4 + (tid & 3)) * 512 + sw23(r & 31) * 8);
      *(uint4*)(kp + fbase)       = pk.u[0];   // hi = 0 (d kk*16 + 0..7)
      *(uint4*)(kp + fbase + 256) = pk.u[1];   // hi = 1 (d kk*16 + 8..15)
      union { bf16_t bs[16]; uint4 u[2]; } pv;
      #pragma unroll
      for (int i = 0; i < 16; ++i) pv.bs[i] = (bf16_t)(raw.f[i] * keep);
      uint4* ldst = (uint4*)&Lt[r][c0];
      ldst[0] = pv.u[0]; ldst[1] = pv.u[1];
    }
    __syncthreads();
    {
      // V fragment-order write: thread (f = tid>>5, vl = tid&31) writes
      // lanes (vl, hi2) of frag f = (i<<2)|ks.
      const int f = tid >> 5;            // 0..7
      const int i_ = f >> 2, ks = f & 3;
      const int vl = tid & 31;
      const int d = i_ * 32 + vl;
      const size_t vbase = bh * 131072 + (size_t)((nt * 8 + f) * 512);
      #pragma unroll
      for (int hi2 = 0; hi2 < 2; ++hi2) {
        union { bf16_t bs[8]; uint4 u; } vp;
        #pragma unroll
        for (int j = 0; j < 8; ++j) vp.bs[j] = Lt[ks * 16 + hi2 * 8 + j][d];
        *(uint4*)(vt + vbase + (hi2 * 32 + vl) * 8) = vp.u;
      }
    }
    __syncthreads();
  }
  if (bx == 0 && tid < B_ * (N_ / 64)) {
    const int b2 = tid >> 5, tt = tid & 31;
    unsigned long long m = 0ull;
    for (int i = 0; i < 64; ++i)
      if (kv_mask[b2 * N_ + tt * 64 + i]) m |= (1ull << i);
    mb[tid] = m;
  }
}

// ---- main: THICK-WAVE flash cross-attn. Each wave owns 64 q-rows x 64 d
//      (4 f32x16 accs) so every ingested K/V byte feeds 2x the MFMA — the
//      data-ingest floor (the r4-r10 wall: 256KB/CU/tile through L1 or LDS)
//      halves. K AND V stream via gload16 DMA of frag-order data into LDS
//      (linear dest; lane-linear conflict-free ds_read_b128; imm-offset
//      addressing), double-buffered, one barrier/tile. Block = 4 waves
//      (2 q-groups x 2 N-halves) = 256 thr; grid 512; 2 blocks/CU;
//      2 waves/SIMD with dual independent q-group chains for ILP.
//      Softmax: poly e^x ~= 1+x+x^2/2 (/8 folded into Q); masked n
//      algebraic (zeroed K'/V + popcount). ----
__global__ __launch_bounds__(256, 2) void attn_kernel(
    const float* __restrict__ q, const bf16_t* __restrict__ kp,
    const bf16_t* __restrict__ vt, const unsigned long long* __restrict__ mb,
    float* __restrict__ out) {
  // staging: K[half][buf] at (half*2+buf)*8192, V at 32768 + same (64KB).
  // epilogue reuses [0,32768) for O^T partials and [32768,33280) for l.
  __shared__ __align__(1024) char smem[65536];

  const int tid  = threadIdx.x;
  const int w    = tid >> 6;     // 0..3
  const int wq   = w & 1;        // 64-row q group
  const int half = w >> 1;       // N-half
  const int lane = tid & 63;
  const int l31  = lane & 31;
  const int hi   = lane >> 5;

  // bijective XCD swizzle (512 wgs % 8 == 0)
  const int wg = (blockIdx.x & 7) * 64 + (blockIdx.x >> 3);
  const int bh = wg >> 3;
  const int m0 = (wg & 7) * 128;
  const int b = bh >> 4, h = bh & 15;

  // DMA sources: this wave stages frags [wq*4, wq*4+4) of its half's tile
  const bf16_t* kgb = kp + (size_t)bh * 131072 + (size_t)half * 65536
                         + (size_t)(wq * 4) * 512 + (size_t)lane * 8;
  const bf16_t* vgb = vt + (size_t)bh * 131072 + (size_t)half * 65536
                         + (size_t)(wq * 4) * 512 + (size_t)lane * 8;

  bf16_t* Kd0 = (bf16_t*)(smem + (half * 2 + 0) * 8192) + wq * 2048;
  bf16_t* Kd1 = (bf16_t*)(smem + (half * 2 + 1) * 8192) + wq * 2048;
  bf16_t* Vd0 = (bf16_t*)(smem + 32768 + (half * 2 + 0) * 8192) + wq * 2048;
  bf16_t* Vd1 = (bf16_t*)(smem + 32768 + (half * 2 + 1) * 8192) + wq * 2048;

  // prologue: stage tile 0 of this half into buffer 0
  #pragma unroll
  for (int i = 0; i < 4; ++i) {
    gload16(kgb + i * 512, Kd0 + i * 512);
    gload16(vgb + i * 512, Vd0 + i * 512);
  }

  // Q: 64 rows/wave (2 groups of 32), pre-scaled by 1/8 (exact 2^-3)
  bf16x8 qb[2][4];
  #pragma unroll
  for (int g = 0; g < 2; ++g) {
    const float* qrow =
        q + ((size_t)(b * M_ + m0 + wq * 64 + g * 32 + l31)) * D_ + h * DH_ + hi * 8;
    float sv[32];
    float ss = 0.f;
    #pragma unroll
    for (int kk = 0; kk < 4; ++kk) {
      float4 a0 = *(const float4*)(qrow + kk * 16);
      float4 a1 = *(const float4*)(qrow + kk * 16 + 4);
      sv[kk * 8 + 0] = silu_f(a0.x); sv[kk * 8 + 1] = silu_f(a0.y);
      sv[kk * 8 + 2] = silu_f(a0.z); sv[kk * 8 + 3] = silu_f(a0.w);
      sv[kk * 8 + 4] = silu_f(a1.x); sv[kk * 8 + 5] = silu_f(a1.y);
      sv[kk * 8 + 6] = silu_f(a1.z); sv[kk * 8 + 7] = silu_f(a1.w);
      #pragma unroll
      for (int i = 0; i < 8; ++i) ss += sv[kk * 8 + i] * sv[kk * 8 + i];
    }
    ss += __shfl_xor(ss, 32);
    const float inv = 0.125f / fmaxf(sqrtf(ss), 1e-6f);
    #pragma unroll
    for (int kk = 0; kk < 4; ++kk) {
      union { unsigned u[4]; bf16x8 v; } pq;
      #pragma unroll
      for (int jj = 0; jj < 4; ++jj)
        pq.u[jj] = pk2(sv[kk * 8 + jj * 2] * inv, sv[kk * 8 + jj * 2 + 1] * inv);
      qb[g][kk] = pq.v;
    }
  }

  f32x16 o00, o01, o10, o11, zvec;
  #pragma unroll
  for (int r = 0; r < 16; ++r) {
    o00[r] = 0.f; o01[r] = 0.f; o10[r] = 0.f; o11[r] = 0.f; zvec[r] = 0.f;
  }
  float lrun0 = 0.f, lrun1 = 0.f;
  unsigned cl = 0, ch = 0;  // masked-n counts for hi=0 / hi=1 lanes
  const unsigned long long* mbb = mb + b * (N_ / 64);

  for (int tt = 0; tt < NTH; ++tt) {
    // barrier: drains DMA for tile tt (implicit vmcnt(0)) and protects the
    // buffer being overwritten (last read at tile tt-1).
    __syncthreads();
    const int cur = tt & 1;
    if (tt + 1 < NTH) {
      const size_t off = (size_t)(tt + 1) * 4096;
      bf16_t* Kd = cur ? Kd0 : Kd1;
      bf16_t* Vd = cur ? Vd0 : Vd1;
      #pragma unroll
      for (int i = 0; i < 4; ++i) {
        gload16(kgb + off + i * 512, Kd + i * 512);
        gload16(vgb + off + i * 512, Vd + i * 512);
      }
    }
    // phantom-mass counts (uniform -> SALU popcount); with sw23 permutation
    // lane hi covers n bits {16c + 8*hi + 0..7}.
    const unsigned long long mk = mbb[half * NTH + tt];
    cl += (unsigned)__popcll(mk & 0x00FF00FF00FF00FFULL);
    ch += (unsigned)__popcll(mk & 0xFF00FF00FF00FF00ULL);

    // lane-linear conflict-free frag reads (base + imm offsets)
    const bf16_t* Kc = (const bf16_t*)(smem + (half * 2 + cur) * 8192) + lane * 8;
    const bf16_t* Vc = (const bf16_t*)(smem + 32768 + (half * 2 + cur) * 8192) + lane * 8;

    bf16x8 ka[2][4];
    #pragma unroll
    for (int nb = 0; nb < 2; ++nb)
      #pragma unroll
      for (int kk = 0; kk < 4; ++kk)
        ka[nb][kk] = *(const bf16x8*)(Kc + (nb * 4 + kk) * 512);

    bf16x8 pa0[4], pa1[4];
    #pragma unroll
    for (int g = 0; g < 2; ++g) {
      #pragma unroll
      for (int nb = 0; nb < 2; ++nb) {
        // S^T = K'(permuted) . Q'^T : col = l31 (m); reg r of lane hi is
        // n_phys = 16*(r>>3) + 8*hi + (r&7) within this nb 32-block
        f32x16 s = __builtin_amdgcn_mfma_f32_32x32x16_bf16(
            ka[nb][0], qb[g][0], zvec, 0, 0, 0);
        #pragma unroll
        for (int kk = 1; kk < 4; ++kk)
          s = __builtin_amdgcn_mfma_f32_32x32x16_bf16(ka[nb][kk], qb[g][kk], s, 0, 0, 0);

        // p = e^x ~= 1 + x + x^2/2 (|x| <= 1/8); poly(0) = 1 EXACTLY
        f32x2 p2[8];
        #pragma unroll
        for (int i = 0; i < 8; ++i) {
          f32x2 x; x.x = s[2 * i]; x.y = s[2 * i + 1];
          f32x2 u = x * 0.5f + 1.0f;
          p2[i] = x * u + 1.0f;
        }
        f32x2 t0 = (p2[0] + p2[1]) + (p2[2] + p2[3]);
        f32x2 t1 = (p2[4] + p2[5]) + (p2[6] + p2[7]);
        f32x2 ts = t0 + t1;
        if (g == 0) lrun0 += ts.x + ts.y; else lrun1 += ts.x + ts.y;

        // P registers ARE the PV B-fragment (sw23 baked into prep)
        union { unsigned u[4]; bf16x8 v; } f0, f1;
        #pragma unroll
        for (int jj = 0; jj < 4; ++jj) {
          f0.u[jj] = pk2(p2[jj].x, p2[jj].y);
          f1.u[jj] = pk2(p2[4 + jj].x, p2[4 + jj].y);
        }
        if (g == 0) { pa0[nb * 2] = f0.v; pa0[nb * 2 + 1] = f1.v; }
        else        { pa1[nb * 2] = f0.v; pa1[nb * 2 + 1] = f1.v; }
      }
    }

    // o^T += V^T . P^T : each V frag feeds BOTH q-groups (2x intensity)
    #pragma unroll
    for (int ks = 0; ks < 4; ++ks) {
      bf16x8 va = *(const bf16x8*)(Vc + ks * 512);
      o00 = __builtin_amdgcn_mfma_f32_32x32x16_bf16(va, pa0[ks], o00, 0, 0, 0);
      o10 = __builtin_amdgcn_mfma_f32_32x32x16_bf16(va, pa1[ks], o10, 0, 0, 0);
    }
    #pragma unroll
    for (int ks = 0; ks < 4; ++ks) {
      bf16x8 va = *(const bf16x8*)(Vc + (4 + ks) * 512);
      o01 = __builtin_amdgcn_mfma_f32_32x32x16_bf16(va, pa0[ks], o01, 0, 0, 0);
      o11 = __builtin_amdgcn_mfma_f32_32x32x16_bf16(va, pa1[ks], o11, 0, 0, 0);
    }
  }

  // subtract phantom mass (p=1 per masked n, exact); fold hi halves.
  const float pm = (float)(hi ? ch : cl);
  lrun0 -= pm; lrun1 -= pm;
  lrun0 += __shfl_xor(lrun0, 32);
  lrun1 += __shfl_xor(lrun1, 32);

  // ---- combine halves + transpose through LDS ----
  __syncthreads();  // all staging reads done; safe to reuse smem
  float* Ob = (float*)smem;                    // [64 d][128 m] f32 = 32KB
  float* Lb = (float*)(smem + 32768);          // [128] f32

  if (half == 0) {
    #pragma unroll
    for (int r = 0; r < 16; ++r) {
      const int d = (r & 3) + ((r >> 2) << 3) + (hi << 2);
      Ob[d * 128 + wq * 64 + l31]             = o00[r];
      Ob[(d + 32) * 128 + wq * 64 + l31]      = o01[r];
      Ob[d * 128 + wq * 64 + 32 + l31]        = o10[r];
      Ob[(d + 32) * 128 + wq * 64 + 32 + l31] = o11[r];
    }
    if (hi == 0) { Lb[wq * 64 + l31] = lrun0; Lb[wq * 64 + 32 + l31] = lrun1; }
  }
  __syncthreads();
  if (half == 1) {
    #pragma unroll
    for (int r = 0; r < 16; ++r) {
      const int d = (r & 3) + ((r >> 2) << 3) + (hi << 2);
      Ob[d * 128 + wq * 64 + l31]             += o00[r];
      Ob[(d + 32) * 128 + wq * 64 + l31]      += o01[r];
      Ob[d * 128 + wq * 64 + 32 + l31]        += o10[r];
      Ob[(d + 32) * 128 + wq * 64 + 32 + l31] += o11[r];
    }
    if (hi == 0) { Lb[wq * 64 + l31] += lrun0; Lb[wq * 64 + 32 + l31] += lrun1; }
  }
  __syncthreads();
  // store: 256 threads over 128 rows; thread covers row m, d [dc, dc+32)
  {
    const int m = tid >> 1, dc = (tid & 1) * 32;
    const float lv = Lb[m];
    const float iv = lv > 0.f ? 1.0f / lv : 0.f;
    float* orow = out + ((size_t)(b * M_ + m0 + m)) * D_ + h * DH_ + dc;
    #pragma unroll
    for (int i0 = 0; i0 < 32; i0 += 4) {
      float4 v;
      v.x = Ob[(dc + i0 + 0) * 128 + m] * iv;
      v.y = Ob[(dc + i0 + 1) * 128 + m] * iv;
      v.z = Ob[(dc + i0 + 2) * 128 + m] * iv;
      v.w = Ob[(dc + i0 + 3) * 128 + m] * iv;
      *(float4*)(orow + i0) = v;
    }
  }
}

extern "C" void kernel_launch(void* const* d_in, const int* in_sizes, int n_in,
                              void* d_out, int out_size, void* d_ws, size_t ws_size,
                              hipStream_t stream) {
  const float* q  = (const float*)d_in[0];
  const float* kv = (const float*)d_in[1];
  const int* kv_mask = (const int*)d_in[2];
  float* out = (float*)d_out;

  // ws layout: K' frags 16MB | V^T frags 16MB | maskbits 1KB
  bf16_t* kp = (bf16_t*)d_ws;
  bf16_t* vt = kp + (size_t)B_ * H_ * N_ * DH_;
  unsigned long long* mb =
      (unsigned long long*)((char*)d_ws + 2 * (size_t)B_ * H_ * N_ * DH_ * sizeof(bf16_t));

  prep_kernel<<<B_ * 32 * 8, 256, 0, stream>>>(kv, kv_mask, kp, vt, mb);
  attn_kernel<<<B_ * H_ * (M_ / 128), 256, 0, stream>>>(q, kp, vt, mb, out);
}